// Round 16
// baseline (34.973 us; speedup 1.0000x reference)
//
#include <hip/hip_runtime.h>
#include <math.h>

#define LOG2E 1.4426950408889634f
typedef __attribute__((ext_vector_type(2))) _Float16 h2v;
typedef __attribute__((ext_vector_type(8))) _Float16 f16x8;
typedef __attribute__((ext_vector_type(4))) float f32x4;

static __device__ __forceinline__ unsigned pkrtz_u32(float lo, float hi) {
  auto p = __builtin_amdgcn_cvt_pkrtz(lo, hi);
  unsigned u; __builtin_memcpy(&u, &p, 4); return u;
}
static __device__ __forceinline__ h2v habs2(h2v x) {
  unsigned u; __builtin_memcpy(&u, &x, 4);
  u &= 0x7FFF7FFFu;
  h2v r; __builtin_memcpy(&r, &u, 4); return r;
}
static __device__ __forceinline__ h2v u2h(unsigned u) {
  h2v r; __builtin_memcpy(&r, &u, 4); return r;
}

// s[i,j] = Ci + Dj + sum_h ab_h*|hq_ih + hkb_jh|, ab=0.05a, Dj=0.075(a.hkb_j)
// Ci per-row -> cancels in softmax -> dropped.
// khT4: [b][h4][j] uint4 = f16 pairs of h=8*h4..8*h4+7 (bias folded).
// hq2t: [rowblock][r 8][it 8][u 4] u32 f16 pairs (per-row contiguous 128B).
// abd2: [h2] u32 pairs of 0.05a.
// vfrag: [b][kstep 32][nt 5][lane 64] uint4 — V in MFMA B-frag order;
//        nt=4 is the ones-column tile (col 64 == 1.0) for the softmax sum.

// ---------------- Kernel A: prep (blocks 0-127) + vpack (blocks 128-255) ------
__global__ __launch_bounds__(256) void prep_kernel(
    const float* __restrict__ qs, const float* __restrict__ ks,
    const float* __restrict__ vs,
    const float* __restrict__ W, const float* __restrict__ bias,
    const float* __restrict__ a,
    unsigned* __restrict__ hq2t, uint4* __restrict__ khT4,
    float* __restrict__ Dj, unsigned* __restrict__ abd2,
    uint4* __restrict__ vfrag) {
  __shared__ __align__(16) float wcomb[64][68];
  __shared__ __align__(16) float xin[64][68];
  const int blk = blockIdx.x;
  const int t = threadIdx.x;

  if (blk >= 128) {  // ---- vpack: V -> MFMA B-fragment f16 layout (5 tiles) ----
    const int unit = blk - 128;             // b = unit>>5, kstep = unit&31
    const int b = unit >> 5, kstep = unit & 31;
    const int lane = t & 63, ntile = t >> 6;
    const int j0 = kstep * 32 + (lane >> 4) * 8;
    const int d = ntile * 16 + (lane & 15);
    const float* vb = vs + b * 1024 * 64;
    unsigned pr[4];
#pragma unroll
    for (int i = 0; i < 4; ++i)
      pr[i] = pkrtz_u32(vb[(j0 + 2 * i) * 64 + d], vb[(j0 + 2 * i + 1) * 64 + d]);
    vfrag[((b * 32 + kstep) * 5 + ntile) * 64 + lane] =
        make_uint4(pr[0], pr[1], pr[2], pr[3]);
    if (t < 64) {  // ones-column tile (nt=4): col 64 == 1.0, rest 0
      unsigned v = ((t & 15) == 0) ? 0x3C003C00u : 0u;
      vfrag[((b * 32 + kstep) * 5 + 4) * 64 + t] = make_uint4(v, v, v, v);
    }
    return;
  }

  const bool qpart = blk < 64;
  const int r0 = (qpart ? blk : blk - 64) * 64;
  const float* src = qpart ? qs : ks;
  if (blk == 0 && t < 32)
    abd2[t] = pkrtz_u32(0.05f * a[2 * t], 0.05f * a[2 * t + 1]);
  for (int rep = 0; rep < 16; ++rep) {
    int e = rep * 256 + t;
    int row = e >> 6, col = e & 63;
    float wd = W[(128 + row) * 64 + col];
    float wm = qpart ? (W[row * 64 + col] + wd)
                     : (W[(64 + row) * 64 + col] - wd);
    wcomb[row][col] = wm;
    xin[row][col] = src[(r0 + row) * 64 + col];
  }
  __syncthreads();
  const int r = t >> 2;
  const int h0 = (t & 3) << 4;
  float acc[16];
#pragma unroll
  for (int k = 0; k < 16; ++k) acc[k] = 0.f;
#pragma unroll 8
  for (int d = 0; d < 64; ++d) {
    float xv = xin[r][d];
#pragma unroll
    for (int c = 0; c < 4; ++c) {
      float4 w4 = *(const float4*)&wcomb[d][h0 + (c << 2)];
      acc[c * 4 + 0] = fmaf(xv, w4.x, acc[c * 4 + 0]);
      acc[c * 4 + 1] = fmaf(xv, w4.y, acc[c * 4 + 1]);
      acc[c * 4 + 2] = fmaf(xv, w4.z, acc[c * 4 + 2]);
      acc[c * 4 + 3] = fmaf(xv, w4.w, acc[c * 4 + 3]);
    }
  }
  int grow = r0 + r;
  if (qpart) {
    unsigned pr[8];
#pragma unroll
    for (int i = 0; i < 8; ++i) pr[i] = pkrtz_u32(acc[2 * i], acc[2 * i + 1]);
    // hq2t[rowblock][r][it][u]: per-(it-pair) contiguous 8 u32
    const int base = (grow >> 3) * 256 + (grow & 7) * 32 + (t & 3) * 8;
    *(uint4*)&hq2t[base]     = make_uint4(pr[0], pr[1], pr[2], pr[3]);
    *(uint4*)&hq2t[base + 4] = make_uint4(pr[4], pr[5], pr[6], pr[7]);
  } else {
    int bidx = grow >> 10;
    int j = grow & 1023;
    float val[16];
    float part = 0.f;
#pragma unroll
    for (int k = 0; k < 16; ++k) {
      val[k] = acc[k] + bias[h0 + k];
      part += a[h0 + k] * val[k];
    }
    part += __shfl_xor(part, 1);
    part += __shfl_xor(part, 2);
    if ((t & 3) == 0) Dj[bidx * 1024 + j] = 0.075f * part;
    unsigned pr[8];
#pragma unroll
    for (int i = 0; i < 8; ++i) pr[i] = pkrtz_u32(val[2 * i], val[2 * i + 1]);
    const int h4a = (t & 3) * 2;
    khT4[(bidx * 8 + h4a) * 1024 + j]     = make_uint4(pr[0], pr[1], pr[2], pr[3]);
    khT4[(bidx * 8 + h4a + 1) * 1024 + j] = make_uint4(pr[4], pr[5], pr[6], pr[7]);
  }
}

// ---------------- Kernel B: 8 rows x 1024 j; k-in-regs score; MFMA PV+sum ----
__global__ __launch_bounds__(512) void attn16_kernel(
    const uint4* __restrict__ vfrag,
    const unsigned* __restrict__ hq2t, const uint4* __restrict__ khT4,
    const float* __restrict__ Dj, const unsigned* __restrict__ abd2,
    float* __restrict__ out) {
  __shared__ __align__(16) unsigned p2u[8 * 520];   // p f16 pairs, row pad
  __shared__ __align__(16) float ob[64 * 64];       // [8w][8r][64d] 16KB
  __shared__ __align__(16) float redm[64];          // [r 8][w 8] per-wave max
  __shared__ __align__(16) float redl[64];          // [w 8][r 8] scaled l

  const int t = threadIdx.x;
  const int lane = t & 63;
  const int w = t >> 6;          // 0..7
  const int b = blockIdx.y;
  const int rowbase = blockIdx.x * 8;
  const int growbase = b * 1024 + rowbase;

  const uint4* kh_b = khT4 + (size_t)b * 8 * 1024;
  const uint4* vf_b = vfrag + (size_t)b * 32 * 5 * 64;
  const unsigned* qt = hq2t + (size_t)(growbase >> 3) * 256;  // [r][it][u]

  const int jloc = w * 128 + lane * 2;  // lane owns j = jloc, jloc+1
  float2 d2 = *(const float2*)(Dj + b * 1024 + jloc);

  // ---- load this lane's ENTIRE k slice into 64 VGPRs (one-time) ----
  uint4 kk[16];
#pragma unroll
  for (int h4 = 0; h4 < 8; ++h4) {
    kk[2 * h4]     = kh_b[h4 * 1024 + jloc];
    kk[2 * h4 + 1] = kh_b[h4 * 1024 + jloc + 1];
  }
  // ---- ab in SGPRs (one-time) ----
  uint4 abv[8];
#pragma unroll
  for (int it = 0; it < 8; ++it) abv[it] = *(const uint4*)(abd2 + it * 4);

  // ---- score rows: pure-register inner loop; q via per-row s_load ----
#pragma unroll 1
  for (int r = 0; r < 8; ++r) {
    uint4 qv[8];
#pragma unroll
    for (int it = 0; it < 8; ++it)
      qv[it] = *(const uint4*)(qt + r * 32 + it * 4);  // uniform -> s_load
    float s0 = 0.f, s1 = 0.f;
#pragma unroll
    for (int it = 0; it < 8; ++it) {
      const unsigned* qu = (const unsigned*)&qv[it];
      const unsigned* au = (const unsigned*)&abv[it];
      const unsigned* k0 = (const unsigned*)&kk[2 * it];
      const unsigned* k1 = (const unsigned*)&kk[2 * it + 1];
#pragma unroll
      for (int u = 0; u < 4; ++u) {
        h2v qh = u2h(qu[u]);
        h2v a2 = u2h(au[u]);
        h2v x0 = habs2(qh + u2h(k0[u]));
        s0 = __builtin_amdgcn_fdot2(a2, x0, s0, false);
        h2v x1 = habs2(qh + u2h(k1[u]));
        s1 = __builtin_amdgcn_fdot2(a2, x1, s1, false);
      }
    }
    s0 += d2.x; s1 += d2.y;
    // per-wave row max + exp + pack (fused per row)
    float m = fmaxf(s0, s1);
#pragma unroll
    for (int off = 32; off >= 1; off >>= 1) m = fmaxf(m, __shfl_xor(m, off));
    if (lane == 0) redm[r * 8 + w] = m;
    float p0 = __builtin_amdgcn_exp2f((s0 - m) * LOG2E);
    float p1 = __builtin_amdgcn_exp2f((s1 - m) * LOG2E);
    p2u[r * 520 + w * 64 + lane] = pkrtz_u32(p0, p1);
  }

  // ---- PV via MFMA (5 n-tiles; nt=4 is the ones column -> row sums) ----
  // (own-wave p2u columns + all rows -> no barrier needed before PV)
  f32x4 acc[5];
#pragma unroll
  for (int nt = 0; nt < 5; ++nt) acc[nt] = (f32x4){0.f, 0.f, 0.f, 0.f};
  const int arow = (lane & 7) * 520;  // A rows 8-15 alias 0-7
  const int kgr = (lane >> 4) * 8;
#pragma unroll 2
  for (int ks = 0; ks < 4; ++ks) {
    const int j0 = w * 128 + ks * 32;
    uint4 au = *(const uint4*)&p2u[arow + ((j0 + kgr) >> 1)];
    f16x8 af; __builtin_memcpy(&af, &au, 16);
    const int gks = j0 >> 5;
#pragma unroll
    for (int nt = 0; nt < 5; ++nt) {
      uint4 bu = vf_b[(gks * 5 + nt) * 64 + lane];
      f16x8 bf; __builtin_memcpy(&bf, &bu, 16);
      acc[nt] = __builtin_amdgcn_mfma_f32_16x16x32_f16(af, bf, acc[nt], 0, 0, 0);
    }
  }
  __syncthreads();  // redm from all waves visible

  // ---- global max per row; rescale factors for this lane's 4 C rows ----
  const int rb = ((lane >> 4) & 1) * 4;
  float sc[4];
#pragma unroll
  for (int rg = 0; rg < 4; ++rg) {
    int r = rb + rg;
    float4 m0 = *(const float4*)&redm[r * 8 + 0];
    float4 m1 = *(const float4*)&redm[r * 8 + 4];
    float M = fmaxf(fmaxf(fmaxf(m0.x, m0.y), fmaxf(m0.z, m0.w)),
                    fmaxf(fmaxf(m1.x, m1.y), fmaxf(m1.z, m1.w)));
    float mwv = redm[r * 8 + w];
    sc[rg] = __builtin_amdgcn_exp2f((mwv - M) * LOG2E);
  }

  // C rows 0-7 live in lanes 0-31: row = (lane>>4)*4 + reg
  if (lane < 32) {
#pragma unroll
    for (int nt = 0; nt < 4; ++nt)
#pragma unroll
      for (int rg = 0; rg < 4; ++rg)
        ob[(w * 8 + rb + rg) * 64 + nt * 16 + (lane & 15)] = acc[nt][rg] * sc[rg];
  }
  if ((lane & 47) == 0) {  // lanes 0,16: l (col 64) for rows rb..rb+3
    float4 lv;
    lv.x = acc[4][0] * sc[0]; lv.y = acc[4][1] * sc[1];
    lv.z = acc[4][2] * sc[2]; lv.w = acc[4][3] * sc[3];
    *(float4*)&redl[w * 8 + rb] = lv;
  }
  __syncthreads();

  // ---- epilogue: cross-wave sum + normalize + store ----
  {
    int r = t >> 6, d = t & 63;  // 512 threads cover 8 rows x 64 d
    float ax = 0.f, lt = 0.f;
#pragma unroll
    for (int wv = 0; wv < 8; ++wv) {
      ax += ob[(wv * 8 + r) * 64 + d];
      lt += redl[wv * 8 + r];
    }
    out[(growbase + r) * 64 + d] = ax / lt;
  }
}

extern "C" void kernel_launch(void* const* d_in, const int* in_sizes, int n_in,
                              void* d_out, int out_size, void* d_ws, size_t ws_size,
                              hipStream_t stream) {
  const float* qs = (const float*)d_in[0];
  const float* ks = (const float*)d_in[1];
  const float* vs = (const float*)d_in[2];
  const float* W  = (const float*)d_in[3];
  const float* bi = (const float*)d_in[4];
  const float* a  = (const float*)d_in[5];
  float* out = (float*)d_out;
  unsigned* hq2t  = (unsigned*)d_ws;                    // 512KB
  uint4*    khT4  = (uint4*)((char*)d_ws + 524288);     // 512KB
  float*    Dj    = (float*)((char*)d_ws + 1048576);    // 16KB
  unsigned* abd2  = (unsigned*)((char*)d_ws + 1064960); // 128B
  uint4*    vfrag = (uint4*)((char*)d_ws + 1065216);    // 640KB
  prep_kernel<<<256, 256, 0, stream>>>(qs, ks, vs, W, bi, a, hq2t, khT4, Dj,
                                       abd2, vfrag);
  attn16_kernel<<<dim3(128, 4), 512, 0, stream>>>(vfrag, hq2t, khT4, Dj, abd2, out);
}

// Round 18
// 31.980 us; speedup vs baseline: 1.0936x; 1.0936x over previous
//
#include <hip/hip_runtime.h>
#include <math.h>

#define LOG2E 1.4426950408889634f
typedef __attribute__((ext_vector_type(2))) _Float16 h2v;
typedef __attribute__((ext_vector_type(8))) _Float16 f16x8;
typedef __attribute__((ext_vector_type(4))) float f32x4;

static __device__ __forceinline__ unsigned pkrtz_u32(float lo, float hi) {
  auto p = __builtin_amdgcn_cvt_pkrtz(lo, hi);
  unsigned u; __builtin_memcpy(&u, &p, 4); return u;
}
static __device__ __forceinline__ h2v habs2(h2v x) {
  unsigned u; __builtin_memcpy(&u, &x, 4);
  u &= 0x7FFF7FFFu;
  h2v r; __builtin_memcpy(&r, &u, 4); return r;
}
static __device__ __forceinline__ h2v u2h(unsigned u) {
  h2v r; __builtin_memcpy(&r, &u, 4); return r;
}
static __device__ __forceinline__ unsigned pkmax_u(unsigned a, unsigned b) {
  h2v r = __builtin_elementwise_max(u2h(a), u2h(b));
  unsigned u; __builtin_memcpy(&u, &r, 4); return u;
}
static __device__ __forceinline__ float h2f(unsigned u, int idx) {
  h2v v = u2h(u);
  return (float)v[idx];
}

// s[i,j] = Ci + Dj + sum_h ab_h*|hq_ih + hkb_jh|, ab=0.05a, Dj=0.075(a.hkb_j)
// Ci per-row -> cancels in softmax -> dropped.
// khT4: [b][h4][j] uint4 = f16 pairs of h=8*h4..8*h4+7 (bias folded).
// hq2t: [rowblock][it 8][r 8][u 4] u32 f16 pairs.
// abd2: [h2] u32 pairs of 0.05a.
// vfrag: [b][kstep 32][nt 5][lane 64] uint4 — V in MFMA B-frag order;
//        nt=4 is the ones-column tile (col 64 == 1.0) for the softmax sum.

// -------- Kernel A: prep GEMM q (0-127) + k (128-255) + vpack (256-383) ------
__global__ __launch_bounds__(256) void prep_kernel(
    const float* __restrict__ qs, const float* __restrict__ ks,
    const float* __restrict__ vs,
    const float* __restrict__ W, const float* __restrict__ bias,
    const float* __restrict__ a,
    unsigned* __restrict__ hq2t, uint4* __restrict__ khT4,
    float* __restrict__ Dj, unsigned* __restrict__ abd2,
    uint4* __restrict__ vfrag) {
  __shared__ __align__(16) float wcomb[64][68];
  __shared__ __align__(16) float xin[32][68];
  const int blk = blockIdx.x;
  const int t = threadIdx.x;

  if (blk >= 256) {  // ---- vpack: V -> MFMA B-fragment f16 layout (5 tiles) ----
    const int unit = blk - 256;             // b = unit>>5, kstep = unit&31
    const int b = unit >> 5, kstep = unit & 31;
    const int lane = t & 63, ntile = t >> 6;
    const int j0 = kstep * 32 + (lane >> 4) * 8;
    const int d = ntile * 16 + (lane & 15);
    const float* vb = vs + b * 1024 * 64;
    unsigned pr[4];
#pragma unroll
    for (int i = 0; i < 4; ++i)
      pr[i] = pkrtz_u32(vb[(j0 + 2 * i) * 64 + d], vb[(j0 + 2 * i + 1) * 64 + d]);
    vfrag[((b * 32 + kstep) * 5 + ntile) * 64 + lane] =
        make_uint4(pr[0], pr[1], pr[2], pr[3]);
    if (t < 64) {  // ones-column tile (nt=4): col 64 == 1.0, rest 0
      unsigned v = ((t & 15) == 0) ? 0x3C003C00u : 0u;
      vfrag[((b * 32 + kstep) * 5 + 4) * 64 + t] = make_uint4(v, v, v, v);
    }
    return;
  }

  const bool qpart = blk < 128;
  const int r0 = (qpart ? blk : blk - 128) * 32;
  const float* src = qpart ? qs : ks;
  if (blk == 0 && t < 32)
    abd2[t] = pkrtz_u32(0.05f * a[2 * t], 0.05f * a[2 * t + 1]);
  // stage wcomb (64x64) and xin (32x64)
  for (int rep = 0; rep < 16; ++rep) {
    int e = rep * 256 + t;
    int row = e >> 6, col = e & 63;
    float wd = W[(128 + row) * 64 + col];
    wcomb[row][col] = qpart ? (W[row * 64 + col] + wd)
                            : (W[(64 + row) * 64 + col] - wd);
  }
  for (int rep = 0; rep < 8; ++rep) {
    int e = rep * 256 + t;
    int row = e >> 6, col = e & 63;
    xin[row][col] = src[(r0 + row) * 64 + col];
  }
  __syncthreads();
  const int r = t >> 3;            // 0..31
  const int h0 = (t & 7) << 3;     // 0,8,..,56
  float acc[8];
#pragma unroll
  for (int k = 0; k < 8; ++k) acc[k] = 0.f;
#pragma unroll 8
  for (int d = 0; d < 64; ++d) {
    float xv = xin[r][d];
    float4 w0 = *(const float4*)&wcomb[d][h0];
    float4 w1 = *(const float4*)&wcomb[d][h0 + 4];
    acc[0] = fmaf(xv, w0.x, acc[0]); acc[1] = fmaf(xv, w0.y, acc[1]);
    acc[2] = fmaf(xv, w0.z, acc[2]); acc[3] = fmaf(xv, w0.w, acc[3]);
    acc[4] = fmaf(xv, w1.x, acc[4]); acc[5] = fmaf(xv, w1.y, acc[5]);
    acc[6] = fmaf(xv, w1.z, acc[6]); acc[7] = fmaf(xv, w1.w, acc[7]);
  }
  const int grow = r0 + r;
  const int it = h0 >> 3;  // h4 group index 0..7
  if (qpart) {
    unsigned pr[4];
#pragma unroll
    for (int i = 0; i < 4; ++i) pr[i] = pkrtz_u32(acc[2 * i], acc[2 * i + 1]);
    // hq2t[rowblock][it][r][u]
    const int base = (grow >> 3) * 256 + it * 32 + (grow & 7) * 4;
    *(uint4*)&hq2t[base] = make_uint4(pr[0], pr[1], pr[2], pr[3]);
  } else {
    const int bidx = grow >> 10;
    const int j = grow & 1023;
    float val[8];
    float part = 0.f;
#pragma unroll
    for (int k = 0; k < 8; ++k) {
      val[k] = acc[k] + bias[h0 + k];
      part += a[h0 + k] * val[k];
    }
    part += __shfl_xor(part, 1);
    part += __shfl_xor(part, 2);
    part += __shfl_xor(part, 4);
    if ((t & 7) == 0) Dj[bidx * 1024 + j] = 0.075f * part;
    unsigned pr[4];
#pragma unroll
    for (int i = 0; i < 4; ++i) pr[i] = pkrtz_u32(val[2 * i], val[2 * i + 1]);
    khT4[(bidx * 8 + it) * 1024 + j] = make_uint4(pr[0], pr[1], pr[2], pr[3]);
  }
}

// ---------------- Kernel B: 8 rows x 1024 j; 8 waves; SMEM q; MFMA PV+sum ----
// (r15's proven attn15 body + s_setprio around the MFMA cluster)
__global__ __launch_bounds__(512) void attn17_kernel(
    const uint4* __restrict__ vfrag,
    const unsigned* __restrict__ hq2t, const uint4* __restrict__ khT4,
    const float* __restrict__ Dj, const unsigned* __restrict__ abd2,
    float* __restrict__ out) {
  __shared__ __align__(16) unsigned p2u[8 * 520];   // p f16 pairs, row pad
  __shared__ __align__(16) float ob[64 * 64];       // [8w][8r][64d] 16KB
  __shared__ __align__(16) unsigned redmu[8 * 4];   // packed per-wave row maxes
  __shared__ __align__(16) float redl[8 * 8];       // [w][r] scaled l partials

  const int t = threadIdx.x;
  const int lane = t & 63;
  const int w = t >> 6;          // 0..7
  const int b = blockIdx.y;
  const int rowbase = blockIdx.x * 8;
  const int growbase = b * 1024 + rowbase;

  const uint4* kh_b = khT4 + (size_t)b * 8 * 1024;
  const uint4* vf_b = vfrag + (size_t)b * 32 * 5 * 64;
  const unsigned* qt = hq2t + (size_t)growbase * 32;  // [it][r][u], wave-uniform

  const int jloc = w * 128 + lane * 2;  // lane owns j = jloc, jloc+1
  float2 d2 = *(const float2*)(Dj + b * 1024 + jloc);

  float s[8][2];
#pragma unroll
  for (int r = 0; r < 8; ++r) { s[r][0] = 0.f; s[r][1] = 0.f; }

  // ---- scores: per h4-group (8 h); k dbuf in VGPRs; q/ab via s_load ----
  uint4 kc0 = kh_b[jloc], kc1 = kh_b[jloc + 1];
#pragma unroll 1
  for (int it = 0; it < 8; ++it) {
    const int nx = (it < 7) ? it + 1 : it;  // last iter: harmless reload
    uint4 kn0 = kh_b[nx * 1024 + jloc];
    uint4 kn1 = kh_b[nx * 1024 + jloc + 1];
    uint4 abq = *(const uint4*)(abd2 + it * 4);             // uniform -> s_load
    const unsigned abu[4] = {abq.x, abq.y, abq.z, abq.w};
    const unsigned kcu[2][4] = {{kc0.x, kc0.y, kc0.z, kc0.w},
                                {kc1.x, kc1.y, kc1.z, kc1.w}};
#pragma unroll
    for (int r = 0; r < 8; ++r) {
      uint4 qq = *(const uint4*)(qt + it * 32 + r * 4);     // uniform -> s_load
      const unsigned qu[4] = {qq.x, qq.y, qq.z, qq.w};
#pragma unroll
      for (int u = 0; u < 4; ++u) {
        h2v qh = u2h(qu[u]);
        h2v a2 = u2h(abu[u]);
        h2v x0 = habs2(qh + u2h(kcu[0][u]));
        s[r][0] = __builtin_amdgcn_fdot2(a2, x0, s[r][0], false);
        h2v x1 = habs2(qh + u2h(kcu[1][u]));
        s[r][1] = __builtin_amdgcn_fdot2(a2, x1, s[r][1], false);
      }
    }
    kc0 = kn0; kc1 = kn1;
  }
#pragma unroll
  for (int r = 0; r < 8; ++r) { s[r][0] += d2.x; s[r][1] += d2.y; }

  // ---- per-wave max via packed f16 butterfly (24 shuffles for all 8 rows) ----
  unsigned mp[4];
#pragma unroll
  for (int k = 0; k < 4; ++k)
    mp[k] = pkrtz_u32(fmaxf(s[2 * k][0], s[2 * k][1]),
                      fmaxf(s[2 * k + 1][0], s[2 * k + 1][1]));
#pragma unroll
  for (int off = 32; off >= 1; off >>= 1) {
#pragma unroll
    for (int k = 0; k < 4; ++k) mp[k] = pkmax_u(mp[k], __shfl_xor(mp[k], off));
  }
  if (lane == 0)
    *(uint4*)&redmu[w * 4] = make_uint4(mp[0], mp[1], mp[2], mp[3]);

  // ---- p = exp2(s - m_w), pack f16 to LDS (own wave's chunk only) ----
#pragma unroll
  for (int r = 0; r < 8; ++r) {
    float mwr = h2f(mp[r >> 1], r & 1);
    float p0 = __builtin_amdgcn_exp2f((s[r][0] - mwr) * LOG2E);
    float p1 = __builtin_amdgcn_exp2f((s[r][1] - mwr) * LOG2E);
    p2u[r * 520 + w * 64 + lane] = pkrtz_u32(p0, p1);
  }

  // ---- PV via MFMA (5 n-tiles; nt=4 is the ones column -> row sums) ----
  f32x4 acc[5];
#pragma unroll
  for (int nt = 0; nt < 5; ++nt) acc[nt] = (f32x4){0.f, 0.f, 0.f, 0.f};
  const int arow = (lane & 7) * 520;  // A rows 8-15 alias 0-7
  const int kgr = (lane >> 4) * 8;
  __builtin_amdgcn_s_setprio(1);
#pragma unroll 2
  for (int ks = 0; ks < 4; ++ks) {
    const int j0 = w * 128 + ks * 32;
    uint4 au = *(const uint4*)&p2u[arow + ((j0 + kgr) >> 1)];
    f16x8 af; __builtin_memcpy(&af, &au, 16);
    const int gks = j0 >> 5;
#pragma unroll
    for (int nt = 0; nt < 5; ++nt) {
      uint4 bu = vf_b[(gks * 5 + nt) * 64 + lane];
      f16x8 bf; __builtin_memcpy(&bf, &bu, 16);
      acc[nt] = __builtin_amdgcn_mfma_f32_16x16x32_f16(af, bf, acc[nt], 0, 0, 0);
    }
  }
  __builtin_amdgcn_s_setprio(0);
  __syncthreads();  // redmu from all waves visible

  // ---- global max (packed, redundant per wave), per-row rescale factors ----
  unsigned Mp[4];
  {
    uint4 v0 = *(const uint4*)&redmu[0];
    Mp[0] = v0.x; Mp[1] = v0.y; Mp[2] = v0.z; Mp[3] = v0.w;
#pragma unroll
    for (int wv = 1; wv < 8; ++wv) {
      uint4 vv = *(const uint4*)&redmu[wv * 4];
      Mp[0] = pkmax_u(Mp[0], vv.x); Mp[1] = pkmax_u(Mp[1], vv.y);
      Mp[2] = pkmax_u(Mp[2], vv.z); Mp[3] = pkmax_u(Mp[3], vv.w);
    }
  }
  const int rb = ((lane >> 4) & 1) * 4;  // this lane's 4 C rows (mod 8)
  float sc[4];
#pragma unroll
  for (int rg = 0; rg < 4; ++rg) {
    int r = rb + rg;
    float mwv = h2f(mp[r >> 1], r & 1);
    float Mv = h2f(Mp[r >> 1], r & 1);
    sc[rg] = __builtin_amdgcn_exp2f((mwv - Mv) * LOG2E);
  }

  // C rows 0-7 live in lanes 0-31: row = (lane>>4)*4 + reg
  if (lane < 32) {
#pragma unroll
    for (int nt = 0; nt < 4; ++nt)
#pragma unroll
      for (int rg = 0; rg < 4; ++rg)
        ob[(w * 8 + rb + rg) * 64 + nt * 16 + (lane & 15)] = acc[nt][rg] * sc[rg];
  }
  if ((lane & 47) == 0) {  // lanes 0,16 hold l (col 64) for rows rb..rb+3
    float4 lv;
    lv.x = acc[4][0] * sc[0]; lv.y = acc[4][1] * sc[1];
    lv.z = acc[4][2] * sc[2]; lv.w = acc[4][3] * sc[3];
    *(float4*)&redl[w * 8 + rb] = lv;
  }
  __syncthreads();

  // ---- epilogue: cross-wave sum + normalize + store ----
  {
    int r = t >> 6, d = t & 63;  // 512 threads cover 8 rows x 64 d
    float ax = 0.f, lt = 0.f;
#pragma unroll
    for (int wv = 0; wv < 8; ++wv) {
      ax += ob[(wv * 8 + r) * 64 + d];
      lt += redl[wv * 8 + r];
    }
    out[(growbase + r) * 64 + d] = ax / lt;
  }
}

extern "C" void kernel_launch(void* const* d_in, const int* in_sizes, int n_in,
                              void* d_out, int out_size, void* d_ws, size_t ws_size,
                              hipStream_t stream) {
  const float* qs = (const float*)d_in[0];
  const float* ks = (const float*)d_in[1];
  const float* vs = (const float*)d_in[2];
  const float* W  = (const float*)d_in[3];
  const float* bi = (const float*)d_in[4];
  const float* a  = (const float*)d_in[5];
  float* out = (float*)d_out;
  unsigned* hq2t  = (unsigned*)d_ws;                    // 512KB
  uint4*    khT4  = (uint4*)((char*)d_ws + 524288);     // 512KB
  float*    Dj    = (float*)((char*)d_ws + 1048576);    // 16KB
  unsigned* abd2  = (unsigned*)((char*)d_ws + 1064960); // 128B
  uint4*    vfrag = (uint4*)((char*)d_ws + 1065216);    // 640KB
  prep_kernel<<<384, 256, 0, stream>>>(qs, ks, vs, W, bi, a, hq2t, khT4, Dj,
                                       abd2, vfrag);
  attn17_kernel<<<dim3(128, 4), 512, 0, stream>>>(vfrag, hq2t, khT4, Dj, abd2, out);
}